// Round 15
// baseline (187.214 us; speedup 1.0000x reference)
//
#include <hip/hip_runtime.h>
#include <cstdint>
#include <cstddef>

#define B_ 4
#define N_ 8192
#define S_ 2048
#define M_ 32768   // B_*N_

typedef short bf16x8 __attribute__((ext_vector_type(8)));
typedef float f32x4 __attribute__((ext_vector_type(4)));

__device__ __forceinline__ float bf2f(unsigned short u) {
  union { unsigned int i; float f; } v; v.i = ((unsigned int)u) << 16; return v.f;
}
__device__ __forceinline__ unsigned short f2bf(float f) {
  union { float f; unsigned int i; } v; v.f = f;
  return (unsigned short)((v.i + 0x7FFFu + ((v.i >> 16) & 1u)) >> 16);
}

// ---------------- pack weights f32 -> bf16 (Wf 256x384, W1 256x256, W2 256x256) ----
__global__ void pack_weights(const float* __restrict__ Wf, const float* __restrict__ W1,
                             const float* __restrict__ W2, unsigned short* __restrict__ out) {
  int i = blockIdx.x * 256 + threadIdx.x;   // grid covers exactly 229376
  float v;
  if (i < 98304)       v = Wf[i];
  else if (i < 163840) v = W1[i - 98304];
  else                 v = W2[i - 163840];
  out[i] = f2bf(v);
}

// ---------------- tiled transpose: src [B][C][Nsp] f32 -> dst rows [(b*Nsp+n)*ldo + coff + c] bf16
__global__ void transpose_to_bf16(const float* __restrict__ src, unsigned short* __restrict__ dst,
                                  int C, int Nsp, int ldo, int coff) {
  __shared__ float t[32][33];
  int b = blockIdx.z;
  int n0 = blockIdx.x * 32, c0 = blockIdx.y * 32;
  int x = threadIdx.x, y = threadIdx.y;
  const float* s = src + ((size_t)b * C + c0) * Nsp + n0;
#pragma unroll
  for (int k = 0; k < 4; ++k)
    t[y + k * 8][x] = s[(size_t)(y + k * 8) * Nsp + x];
  __syncthreads();
#pragma unroll
  for (int k = 0; k < 4; ++k) {
    int n = n0 + y + k * 8;
    dst[((size_t)b * Nsp + n) * ldo + coff + c0 + x] = f2bf(t[x][y + k * 8]);
  }
}

// lexicographic (d, idx) strict less-than: matches top_k's stable tie-break
__device__ __forceinline__ bool lexlt(float da, int ia, float db, int ib) {
  return (da < db) || (da == db && ia < ib);
}

// ---------------- 3-NN + inverse-distance interpolation ----------------
// grid 512, block 256 (4 waves). Each wave owns 16 queries; each LANE owns 4
// queries (qquad = lane>>4) and scans candidate slice sub = lane&15 (128 cands),
// evaluating all 4 queries per float4 LDS read -> LDS instructions / 4 vs the
// 1-query-per-lane version (R11 evidence: VALU trim didn't move time => LDS
// pipe was the co-limit). Scan order, update arithmetic, and the 4-stage
// shfl_xor merge are bit-identical to R11 per query.
__global__ __launch_bounds__(256) void knn_interp_kernel(
    const float* __restrict__ xyz1, const float* __restrict__ xyz2,
    const unsigned short* __restrict__ p2t, unsigned short* __restrict__ np) {
  __shared__ float4 sp[1024];        // 16 KB candidate chunk (xyz, |c|^2)
  __shared__ float sw[64][3];
  __shared__ int   sidx[64][3];
  int t = threadIdx.x;
  int bx = blockIdx.x;
  int b = bx >> 7;                   // 128 blocks per batch
  const float* xb = xyz2 + (size_t)b * S_ * 3;

  int lane = t & 63, wave = t >> 6;
  int sub = lane & 15;               // candidate slice
  int qquad = lane >> 4;             // which 4-query group within the wave
  int qloc = wave * 16 + qquad * 4;  // first of this lane's 4 queries (block-local)
  size_t gq0 = (size_t)b * N_ + (size_t)(bx & 127) * 64 + qloc;

  float px[4], py[4], pz[4], nx[4], ny[4], nz[4], aa[4];
#pragma unroll
  for (int k = 0; k < 4; ++k) {
    const float* q = xyz1 + (gq0 + k) * 3;
    px[k] = q[0]; py[k] = q[1]; pz[k] = q[2];
    nx[k] = -2.f * px[k]; ny[k] = -2.f * py[k]; nz[k] = -2.f * pz[k];
    aa[k] = fmaf(px[k], px[k], fmaf(py[k], py[k], pz[k] * pz[k]));
  }

  float d0[4], d1[4], d2[4];
  int i0[4], i1[4], i2[4];
#pragma unroll
  for (int k = 0; k < 4; ++k) {
    d0[k] = 1e30f; d1[k] = 1e30f; d2[k] = 1e30f;
    i0[k] = S_; i1[k] = S_; i2[k] = S_;
  }

  for (int chunk = 0; chunk < 2; ++chunk) {
    __syncthreads();                 // previous chunk's readers done
    for (int i = t; i < 1024; i += 256) {
      int c = chunk * 1024 + i;
      float cx = xb[3 * c], cy = xb[3 * c + 1], cz = xb[3 * c + 2];
      sp[i] = make_float4(cx, cy, cz, fmaf(cx, cx, fmaf(cy, cy, cz * cz)));
    }
    __syncthreads();
    int sbase = chunk * 1024;
#pragma unroll 2
    for (int i = 0; i < 64; ++i) {
      int sl = i * 16 + sub;
      float4 c = sp[sl];
      int s = sbase + sl;
#pragma unroll
      for (int k = 0; k < 4; ++k) {
        float d = fmaf(nx[k], c.x, fmaf(ny[k], c.y, fmaf(nz[k], c.z, c.w)));
        // scan visits indices in increasing order; strict < keeps lower index on ties
        bool b0 = d < d0[k], b1 = d < d1[k], b2 = d < d2[k];
        i2[k] = b1 ? i1[k] : (b2 ? s : i2[k]);
        i1[k] = b0 ? i0[k] : (b1 ? s : i1[k]);
        i0[k] = b0 ? s : i0[k];
        float nd1 = __builtin_amdgcn_fmed3f(d, d0[k], d1[k]);
        float nd2 = __builtin_amdgcn_fmed3f(d, d1[k], d2[k]);
        d0[k] = fminf(d0[k], d);
        d1[k] = nd1; d2[k] = nd2;
      }
    }
  }

  // merge sorted triples across the 16 sub-lanes of each qquad group (per query).
  // k-th smallest of union = min_{i+j=k} max(a_i, b_j)
#pragma unroll
  for (int k = 0; k < 4; ++k) {
#pragma unroll
    for (int m = 1; m <= 8; m <<= 1) {
      float e0 = __shfl_xor(d0[k], m, 64), e1 = __shfl_xor(d1[k], m, 64), e2 = __shfl_xor(d2[k], m, 64);
      int   j0 = __shfl_xor(i0[k], m, 64), j1 = __shfl_xor(i1[k], m, 64), j2 = __shfl_xor(i2[k], m, 64);
      bool l0 = lexlt(d0[k], i0[k], e0, j0);
      float m0d = l0 ? d0[k] : e0;  int m0i = l0 ? i0[k] : j0;   // min(a0,b0)
      float x0d = l0 ? e0 : d0[k];  int x0i = l0 ? j0 : i0[k];   // max(a0,b0)
      bool l11 = lexlt(d1[k], i1[k], e1, j1);
      float n1d = l11 ? d1[k] : e1; int n1i = l11 ? i1[k] : j1;  // min(a1,b1)
      bool l1 = lexlt(n1d, n1i, x0d, x0i);
      float m1d = l1 ? n1d : x0d; int m1i = l1 ? n1i : x0i;      // 2nd smallest
      bool l01 = lexlt(d0[k], i0[k], e1, j1);
      float p1d = l01 ? e1 : d0[k]; int p1i = l01 ? j1 : i0[k];  // max(a0,b1)
      bool l10 = lexlt(d1[k], i1[k], e0, j0);
      float p2d = l10 ? e0 : d1[k]; int p2i = l10 ? j0 : i1[k];  // max(a1,b0)
      bool lp = lexlt(p1d, p1i, p2d, p2i);
      float p3d = lp ? p1d : p2d; int p3i = lp ? p1i : p2i;
      bool l22 = lexlt(d2[k], i2[k], e2, j2);
      float p4d = l22 ? d2[k] : e2; int p4i = l22 ? i2[k] : j2;  // min(a2,b2)
      bool l2 = lexlt(p3d, p3i, p4d, p4i);
      float m2d = l2 ? p3d : p4d; int m2i = l2 ? p3i : p4i;      // 3rd smallest
      d0[k] = m0d; i0[k] = m0i; d1[k] = m1d; i1[k] = m1i; d2[k] = m2d; i2[k] = m2i;
    }
  }

  if (sub == 0) {
#pragma unroll
    for (int k = 0; k < 4; ++k) {
      float t0 = aa[k] + d0[k], t1 = aa[k] + d1[k], t2 = aa[k] + d2[k];
      float r0 = 1.f / (t0 + 1e-8f), r1 = 1.f / (t1 + 1e-8f), r2 = 1.f / (t2 + 1e-8f);
      float rs = 1.f / (r0 + r1 + r2);
      sw[qloc + k][0] = r0 * rs; sw[qloc + k][1] = r1 * rs; sw[qloc + k][2] = r2 * rs;
      sidx[qloc + k][0] = i0[k]; sidx[qloc + k][1] = i1[k]; sidx[qloc + k][2] = i2[k];
    }
  }
  __syncthreads();

  // gather + weighted sum -> new_points[:, 128:384]
  size_t grow0 = (size_t)b * N_ + (size_t)(bx & 127) * 64;
  for (int p = wave; p < 64; p += 4) {
    float w0 = sw[p][0], w1 = sw[p][1], w2 = sw[p][2];
    const ushort4* g0 = (const ushort4*)(p2t + ((size_t)b * S_ + sidx[p][0]) * 256) + lane;
    const ushort4* g1 = (const ushort4*)(p2t + ((size_t)b * S_ + sidx[p][1]) * 256) + lane;
    const ushort4* g2 = (const ushort4*)(p2t + ((size_t)b * S_ + sidx[p][2]) * 256) + lane;
    ushort4 a = *g0, c = *g1, e = *g2;
    ushort4 o;
    o.x = f2bf(w0 * bf2f(a.x) + w1 * bf2f(c.x) + w2 * bf2f(e.x));
    o.y = f2bf(w0 * bf2f(a.y) + w1 * bf2f(c.y) + w2 * bf2f(e.y));
    o.z = f2bf(w0 * bf2f(a.z) + w1 * bf2f(c.z) + w2 * bf2f(e.z));
    o.w = f2bf(w0 * bf2f(a.w) + w1 * bf2f(c.w) + w2 * bf2f(e.w));
    *((ushort4*)(np + (grow0 + p) * 384 + 128) + lane) = o;
  }
}

// ---------------- bf16 GEMM (m97 structure, BK=64): C[M][256] = A[M][K] * W[256][K]^T
// grid (M/128, 256/128), block 256 (4 waves, 2x2), BK=64, 16x16x32 bf16 MFMA.
// BK=128 regressed (R12, m132-consistent); BK=64 is pinned.
__global__ __launch_bounds__(256) void gemm_bt(const unsigned short* __restrict__ A,
                                               const unsigned short* __restrict__ Bw,
                                               float* __restrict__ C, int K) {
  __shared__ unsigned short As[128 * 64];
  __shared__ unsigned short Bs[128 * 64];
  int tid = threadIdx.x;
  int lane = tid & 63, wave = tid >> 6;
  int wr = wave >> 1, wc = wave & 1;
  size_t m0 = (size_t)blockIdx.x * 128;
  int n0 = blockIdx.y * 128;
  int lr = lane & 15, lk = lane >> 4;
  f32x4 acc[4][4] = {};

  for (int kt = 0; kt < K; kt += 64) {
#pragma unroll
    for (int i = 0; i < 4; ++i) {
      int ch = i * 256 + tid;
      int row = ch >> 3;
      int col = (ch & 7) * 8;
      __builtin_amdgcn_global_load_lds(
          (const __attribute__((address_space(1))) void*)(A + (m0 + row) * K + kt + col),
          (__attribute__((address_space(3))) void*)(As + ch * 8), 16, 0, 0);
    }
#pragma unroll
    for (int i = 0; i < 4; ++i) {
      int ch = i * 256 + tid;
      int row = ch >> 3;
      int col = (ch & 7) * 8;
      __builtin_amdgcn_global_load_lds(
          (const __attribute__((address_space(1))) void*)(Bw + (size_t)(n0 + row) * K + kt + col),
          (__attribute__((address_space(3))) void*)(Bs + ch * 8), 16, 0, 0);
    }
    __syncthreads();

    bf16x8 af[4][2], bf[4][2];
#pragma unroll
    for (int m = 0; m < 4; ++m)
#pragma unroll
      for (int kk = 0; kk < 2; ++kk)
        af[m][kk] = *(const bf16x8*)(As + (wr * 64 + m * 16 + lr) * 64 + kk * 32 + lk * 8);
#pragma unroll
    for (int nn = 0; nn < 4; ++nn)
#pragma unroll
      for (int kk = 0; kk < 2; ++kk)
        bf[nn][kk] = *(const bf16x8*)(Bs + (wc * 64 + nn * 16 + lr) * 64 + kk * 32 + lk * 8);

#pragma unroll
    for (int m = 0; m < 4; ++m)
#pragma unroll
      for (int nn = 0; nn < 4; ++nn)
#pragma unroll
        for (int kk = 0; kk < 2; ++kk)
          acc[m][nn] = __builtin_amdgcn_mfma_f32_16x16x32_bf16(af[m][kk], bf[nn][kk], acc[m][nn], 0, 0, 0);
    __syncthreads();
  }

  // C/D layout (m89): col = lane&15, row = (lane>>4)*4 + j
#pragma unroll
  for (int m = 0; m < 4; ++m) {
    size_t row = m0 + wr * 64 + m * 16 + lk * 4;
#pragma unroll
    for (int j = 0; j < 4; ++j) {
      float* cr = C + (row + j) * 256 + n0 + wc * 64 + lr;
#pragma unroll
      for (int nn = 0; nn < 4; ++nn)
        cr[nn * 16] = acc[m][nn][j];
    }
  }
}

// ---------------- per-channel sum / sumsq over rows of X [M][256] ----------------
// grid 128 (256 rows each), block 256 = channel. Grid sweep R11/R13/R14:
// @128=160.6 total, @256=166, @512=184 -> atomic same-address serialization
// (~50cyc/add) dominates; 128 blocks/address is the measured optimum.
__global__ void col_stats(const float* __restrict__ X, float* __restrict__ sums) {
  int c = threadIdx.x;
  size_t r0 = (size_t)blockIdx.x * 256;
  float s0 = 0, s1 = 0, s2 = 0, s3 = 0, q0 = 0, q1 = 0, q2 = 0, q3 = 0;
  for (int r = 0; r < 256; r += 4) {
    float v0 = X[(r0 + r + 0) * 256 + c];
    float v1 = X[(r0 + r + 1) * 256 + c];
    float v2 = X[(r0 + r + 2) * 256 + c];
    float v3 = X[(r0 + r + 3) * 256 + c];
    s0 += v0; q0 += v0 * v0;
    s1 += v1; q1 += v1 * v1;
    s2 += v2; q2 += v2 * v2;
    s3 += v3; q3 += v3 * v3;
  }
  atomicAdd(&sums[c], s0 + s1 + s2 + s3);
  atomicAdd(&sums[256 + c], q0 + q1 + q2 + q3);
}

// ---------------- BN (train) + ReLU + cast bf16: Y[M][256] ----------------
__global__ void bn_relu_kernel(const float* __restrict__ X, const float* __restrict__ sums,
                               const float* __restrict__ g, const float* __restrict__ be,
                               unsigned short* __restrict__ Y) {
  __shared__ float sc[256], sh[256];
  int t = threadIdx.x;
  {
    float s = sums[t], q = sums[256 + t];
    float m = s * (1.0f / 32768.0f);
    float v = q * (1.0f / 32768.0f) - m * m;
    float scale = g[t] * rsqrtf(v + 1e-5f);
    sc[t] = scale; sh[t] = be[t] - m * scale;
  }
  __syncthreads();
  const float4* X4 = (const float4*)X;
  ushort4* Y4 = (ushort4*)Y;
  for (size_t i = (size_t)blockIdx.x * 256 + t; i < (size_t)M_ * 64; i += 2048 * 256) {
    float4 x = X4[i];
    int c0 = (int)((i * 4) & 255);
    ushort4 o;
    o.x = f2bf(fmaxf(x.x * sc[c0 + 0] + sh[c0 + 0], 0.f));
    o.y = f2bf(fmaxf(x.y * sc[c0 + 1] + sh[c0 + 1], 0.f));
    o.z = f2bf(fmaxf(x.z * sc[c0 + 2] + sh[c0 + 2], 0.f));
    o.w = f2bf(fmaxf(x.w * sc[c0 + 3] + sh[c0 + 3], 0.f));
    Y4[i] = o;
  }
}

// ---------------- final: out[b][o][n] = relu(x + BN2(z)), tiled transpose ----------------
__global__ void final_kernel(const float* __restrict__ Z, const unsigned short* __restrict__ Xb,
                             const float* __restrict__ sums2, const float* __restrict__ g2,
                             const float* __restrict__ be2, float* __restrict__ out) {
  __shared__ float sc[64], sh[64];
  __shared__ float tile[64 * 65];
  int t = threadIdx.x;
  int o0 = blockIdx.y * 64;
  if (t < 64) {
    int c = o0 + t;
    float s = sums2[c], q = sums2[256 + c];
    float m = s * (1.0f / 32768.0f);
    float v = q * (1.0f / 32768.0f) - m * m;
    float scale = g2[c] * rsqrtf(v + 1e-5f);
    sc[t] = scale; sh[t] = be2[c] - m * scale;
  }
  __syncthreads();
  size_t m0 = (size_t)blockIdx.x * 64;
  int rl = t >> 4, cq = t & 15;
#pragma unroll
  for (int rr = 0; rr < 4; ++rr) {
    int row = rr * 16 + rl;
    size_t base = (m0 + row) * 256 + o0 + cq * 4;
    float4 z = *(const float4*)(Z + base);
    ushort4 x = *(const ushort4*)(Xb + base);
    int c = cq * 4;
    tile[row * 65 + c + 0] = fmaxf(z.x * sc[c + 0] + sh[c + 0] + bf2f(x.x), 0.f);
    tile[row * 65 + c + 1] = fmaxf(z.y * sc[c + 1] + sh[c + 1] + bf2f(x.y), 0.f);
    tile[row * 65 + c + 2] = fmaxf(z.z * sc[c + 2] + sh[c + 2] + bf2f(x.z), 0.f);
    tile[row * 65 + c + 3] = fmaxf(z.w * sc[c + 3] + sh[c + 3] + bf2f(x.w), 0.f);
  }
  __syncthreads();
  int b = (int)(m0 >> 13);
  int nbase = (int)(m0 & 8191);
  int orow = t >> 4, nq = t & 15;
#pragma unroll
  for (int ov = 0; ov < 4; ++ov) {
    int o = ov * 16 + orow;
    float4 v;
    v.x = tile[(nq * 4 + 0) * 65 + o];
    v.y = tile[(nq * 4 + 1) * 65 + o];
    v.z = tile[(nq * 4 + 2) * 65 + o];
    v.w = tile[(nq * 4 + 3) * 65 + o];
    *(float4*)(out + ((size_t)(b * 256 + o0 + o)) * 8192 + nbase + nq * 4) = v;
  }
}

extern "C" void kernel_launch(void* const* d_in, const int* in_sizes, int n_in,
                              void* d_out, int out_size, void* d_ws, size_t ws_size,
                              hipStream_t stream) {
  const float* xyz1    = (const float*)d_in[0];
  const float* xyz2    = (const float*)d_in[1];
  const float* points1 = (const float*)d_in[2];
  const float* points2 = (const float*)d_in[3];
  const float* W_fuse  = (const float*)d_in[4];
  // biases d_in[5], d_in[9], d_in[13] cancel exactly under training-mode BN
  const float* g_fuse  = (const float*)d_in[6];
  const float* be_fuse = (const float*)d_in[7];
  const float* W1      = (const float*)d_in[8];
  const float* g1      = (const float*)d_in[10];
  const float* be1     = (const float*)d_in[11];
  const float* W2      = (const float*)d_in[12];
  const float* g2      = (const float*)d_in[14];
  const float* be2     = (const float*)d_in[15];
  float* out = (float*)d_out;

  char* ws = (char*)d_ws;
  float* lin = (float*)ws;                   ws += (size_t)M_ * 256 * 4;   // 33.5 MB, reused 3x
  unsigned short* xb = (unsigned short*)ws;  ws += (size_t)M_ * 256 * 2;   // 16.8 MB
  unsigned short* np = (unsigned short*)ws;  ws += (size_t)M_ * 384 * 2;   // 25.2 MB (yb aliases np)
  unsigned short* yb = np;                                                  // np dead after fuse GEMM
  unsigned short* p2t = (unsigned short*)ws; ws += (size_t)B_ * S_ * 256 * 2; // 4.2 MB
  unsigned short* wb = (unsigned short*)ws;  ws += 229376 * 2;
  float* stats = (float*)ws;                 // 6*256 floats

  hipMemsetAsync(stats, 0, 6 * 256 * sizeof(float), stream);
  pack_weights<<<896, 256, 0, stream>>>(W_fuse, W1, W2, wb);
  // points1 -> new_points[:, 0:128]
  transpose_to_bf16<<<dim3(256, 4, 4), dim3(32, 8), 0, stream>>>(points1, np, 128, N_, 384, 0);
  // points2 -> p2t [B][S][256]
  transpose_to_bf16<<<dim3(64, 8, 4), dim3(32, 8), 0, stream>>>(points2, p2t, 256, S_, 256, 0);
  // 3-NN interp -> new_points[:, 128:384]
  knn_interp_kernel<<<512, 256, 0, stream>>>(xyz1, xyz2, p2t, np);
  // fuse layer
  gemm_bt<<<dim3(M_ / 128, 2), 256, 0, stream>>>(np, wb, lin, 384);
  col_stats<<<128, 256, 0, stream>>>(lin, stats);
  bn_relu_kernel<<<2048, 256, 0, stream>>>(lin, stats, g_fuse, be_fuse, xb);
  // residual block conv1
  gemm_bt<<<dim3(M_ / 128, 2), 256, 0, stream>>>(xb, wb + 98304, lin, 256);
  col_stats<<<128, 256, 0, stream>>>(lin, stats + 512);
  bn_relu_kernel<<<2048, 256, 0, stream>>>(lin, stats + 512, g1, be1, yb);
  // residual block conv2
  gemm_bt<<<dim3(M_ / 128, 2), 256, 0, stream>>>(yb, wb + 163840, lin, 256);
  col_stats<<<128, 256, 0, stream>>>(lin, stats + 1024);
  // BN2 + residual + relu + transpose to [B][256][N]
  final_kernel<<<dim3(M_ / 64, 4), 256, 0, stream>>>(lin, xb, stats + 1024, g2, be2, out);
}

// Round 16
// 157.500 us; speedup vs baseline: 1.1887x; 1.1887x over previous
//
#include <hip/hip_runtime.h>
#include <cstdint>
#include <cstddef>

#define B_ 4
#define N_ 8192
#define S_ 2048
#define M_ 32768   // B_*N_

typedef short bf16x8 __attribute__((ext_vector_type(8)));
typedef float f32x4 __attribute__((ext_vector_type(4)));

__device__ __forceinline__ float bf2f(unsigned short u) {
  union { unsigned int i; float f; } v; v.i = ((unsigned int)u) << 16; return v.f;
}
__device__ __forceinline__ unsigned short f2bf(float f) {
  union { float f; unsigned int i; } v; v.f = f;
  return (unsigned short)((v.i + 0x7FFFu + ((v.i >> 16) & 1u)) >> 16);
}

// ---------------- pack weights f32 -> bf16 + zero stats (fused memset) ----------------
__global__ void pack_weights(const float* __restrict__ Wf, const float* __restrict__ W1,
                             const float* __restrict__ W2, unsigned short* __restrict__ out,
                             float* __restrict__ stats) {
  int i = blockIdx.x * 256 + threadIdx.x;   // grid covers exactly 229376
  if (blockIdx.x == 0) {
#pragma unroll
    for (int k = 0; k < 6; ++k) stats[k * 256 + threadIdx.x] = 0.f;
  }
  float v;
  if (i < 98304)       v = Wf[i];
  else if (i < 163840) v = W1[i - 98304];
  else                 v = W2[i - 163840];
  out[i] = f2bf(v);
}

// ---------------- combined tiled transposes (both jobs, one dispatch) ----------------
// grid dim3(1536, 1, B_), block (32,8).
// bx < 1024: points1 [B][128][8192] f32 -> np rows ld=384 coff=0   (256 x 4 tiles)
// bx >= 1024: points2 [B][256][2048] f32 -> p2t rows ld=256 coff=0 ( 64 x 8 tiles)
__global__ void transpose_both(const float* __restrict__ points1, unsigned short* __restrict__ np,
                               const float* __restrict__ points2, unsigned short* __restrict__ p2t) {
  __shared__ float t[32][33];
  int bx = blockIdx.x;
  int b = blockIdx.z;
  const float* src; unsigned short* dst;
  int C, Nsp, ldo, n0, c0;
  if (bx < 1024) {
    src = points1; dst = np; C = 128; Nsp = 8192; ldo = 384;
    n0 = (bx & 255) * 32; c0 = (bx >> 8) * 32;
  } else {
    int j = bx - 1024;
    src = points2; dst = p2t; C = 256; Nsp = 2048; ldo = 256;
    n0 = (j & 63) * 32; c0 = (j >> 6) * 32;
  }
  int x = threadIdx.x, y = threadIdx.y;
  const float* s = src + ((size_t)b * C + c0) * Nsp + n0;
#pragma unroll
  for (int k = 0; k < 4; ++k)
    t[y + k * 8][x] = s[(size_t)(y + k * 8) * Nsp + x];
  __syncthreads();
#pragma unroll
  for (int k = 0; k < 4; ++k) {
    int n = n0 + y + k * 8;
    dst[((size_t)b * Nsp + n) * ldo + c0 + x] = f2bf(t[x][y + k * 8]);
  }
}

// lexicographic (d, idx) strict less-than: matches top_k's stable tie-break
__device__ __forceinline__ bool lexlt(float da, int ia, float db, int ib) {
  return (da < db) || (da == db && ia < ib);
}

// ---------------- 3-NN + inverse-distance interpolation (R11 version, 40.7us, PINNED) ----
// grid (N_/16, B_), block 256 (4 waves, 16 queries/block). 16 lanes per query,
// each scans 128 candidates ranked by key = |c|^2 - 2 p.c. Candidates staged in
// two 16 KB LDS chunks so 8 blocks/CU fit (8192 waves total -- TLP is the
// latency-hiding mechanism; both lower-wave restructures regressed, R7/R15).
// Value path fmin/fmed3; index path cndmask with scan-order tie-break;
// 4-stage shfl_xor merge of sorted (d,idx) triples.
__global__ __launch_bounds__(256, 8) void knn_interp_kernel(
    const float* __restrict__ xyz1, const float* __restrict__ xyz2,
    const unsigned short* __restrict__ p2t, unsigned short* __restrict__ np) {
  __shared__ float4 sp[1024];        // 16 KB candidate chunk (xyz, |c|^2)
  __shared__ float sw[16][3];
  __shared__ int   sidx[16][3];
  int t = threadIdx.x;
  int b = blockIdx.y;
  const float* xb = xyz2 + (size_t)b * S_ * 3;

  int lane = t & 63, wave = t >> 6;
  int sub = lane & 15;               // which 1/16 of candidate set
  int pib = wave * 4 + (lane >> 4);  // point in block (0..15)
  int n = blockIdx.x * 16 + pib;
  const float* q = xyz1 + ((size_t)b * N_ + n) * 3;
  float px = q[0], py = q[1], pz = q[2];
  float nx = -2.f * px, ny = -2.f * py, nz = -2.f * pz;
  float aa = fmaf(px, px, fmaf(py, py, pz * pz));

  float d0 = 1e30f, d1 = 1e30f, d2 = 1e30f;
  int i0 = S_, i1 = S_, i2 = S_;

  for (int chunk = 0; chunk < 2; ++chunk) {
    __syncthreads();                 // previous chunk's readers done
    for (int i = t; i < 1024; i += 256) {
      int c = chunk * 1024 + i;
      float cx = xb[3 * c], cy = xb[3 * c + 1], cz = xb[3 * c + 2];
      sp[i] = make_float4(cx, cy, cz, fmaf(cx, cx, fmaf(cy, cy, cz * cz)));
    }
    __syncthreads();
    int sbase = chunk * 1024;
#pragma unroll 8
    for (int i = 0; i < 64; ++i) {
      int sl = i * 16 + sub;
      float4 c = sp[sl];
      float d = fmaf(nx, c.x, fmaf(ny, c.y, fmaf(nz, c.z, c.w)));  // |c|^2 - 2 p.c
      int s = sbase + sl;
      // scan visits indices in increasing order, so strict < keeps lower index on ties
      bool b0 = d < d0, b1 = d < d1, b2 = d < d2;
      i2 = b1 ? i1 : (b2 ? s : i2);
      i1 = b0 ? i0 : (b1 ? s : i1);
      i0 = b0 ? s : i0;
      // value path: identical results to the cndmask chain, 3 ops instead of 5
      float nd1 = __builtin_amdgcn_fmed3f(d, d0, d1);
      float nd2 = __builtin_amdgcn_fmed3f(d, d1, d2);
      d0 = fminf(d0, d);
      d1 = nd1; d2 = nd2;
    }
  }

  // merge sorted triples across the 16 lanes of each query group.
  // k-th smallest of union = min_{i+j=k} max(a_i, b_j)  (order-statistic identity)
#pragma unroll
  for (int m = 1; m <= 8; m <<= 1) {
    float e0 = __shfl_xor(d0, m, 64), e1 = __shfl_xor(d1, m, 64), e2 = __shfl_xor(d2, m, 64);
    int   j0 = __shfl_xor(i0, m, 64), j1 = __shfl_xor(i1, m, 64), j2 = __shfl_xor(i2, m, 64);
    bool l0 = lexlt(d0, i0, e0, j0);
    float m0d = l0 ? d0 : e0;  int m0i = l0 ? i0 : j0;   // min(a0,b0)
    float x0d = l0 ? e0 : d0;  int x0i = l0 ? j0 : i0;   // max(a0,b0)
    bool l11 = lexlt(d1, i1, e1, j1);
    float n1d = l11 ? d1 : e1; int n1i = l11 ? i1 : j1;  // min(a1,b1)
    bool l1 = lexlt(n1d, n1i, x0d, x0i);
    float m1d = l1 ? n1d : x0d; int m1i = l1 ? n1i : x0i;        // 2nd smallest
    bool l01 = lexlt(d0, i0, e1, j1);
    float p1d = l01 ? e1 : d0; int p1i = l01 ? j1 : i0;  // max(a0,b1)
    bool l10 = lexlt(d1, i1, e0, j0);
    float p2d = l10 ? e0 : d1; int p2i = l10 ? j0 : i1;  // max(a1,b0)
    bool lp = lexlt(p1d, p1i, p2d, p2i);
    float p3d = lp ? p1d : p2d; int p3i = lp ? p1i : p2i;
    bool l22 = lexlt(d2, i2, e2, j2);
    float p4d = l22 ? d2 : e2; int p4i = l22 ? i2 : j2;  // min(a2,b2)
    bool l2 = lexlt(p3d, p3i, p4d, p4i);
    float m2d = l2 ? p3d : p4d; int m2i = l2 ? p3i : p4i;        // 3rd smallest
    d0 = m0d; i0 = m0i; d1 = m1d; i1 = m1i; d2 = m2d; i2 = m2i;
  }

  if (sub == 0) {
    float t0 = aa + d0, t1 = aa + d1, t2 = aa + d2;   // true squared distances
    float r0 = 1.f / (t0 + 1e-8f), r1 = 1.f / (t1 + 1e-8f), r2 = 1.f / (t2 + 1e-8f);
    float rs = 1.f / (r0 + r1 + r2);
    sw[pib][0] = r0 * rs; sw[pib][1] = r1 * rs; sw[pib][2] = r2 * rs;
    sidx[pib][0] = i0; sidx[pib][1] = i1; sidx[pib][2] = i2;
  }
  __syncthreads();

  // gather + weighted sum -> new_points[:, 128:384]
  for (int p = wave; p < 16; p += 4) {
    float w0 = sw[p][0], w1 = sw[p][1], w2 = sw[p][2];
    const ushort4* g0 = (const ushort4*)(p2t + ((size_t)b * S_ + sidx[p][0]) * 256) + lane;
    const ushort4* g1 = (const ushort4*)(p2t + ((size_t)b * S_ + sidx[p][1]) * 256) + lane;
    const ushort4* g2 = (const ushort4*)(p2t + ((size_t)b * S_ + sidx[p][2]) * 256) + lane;
    ushort4 a = *g0, c = *g1, e = *g2;
    ushort4 o;
    o.x = f2bf(w0 * bf2f(a.x) + w1 * bf2f(c.x) + w2 * bf2f(e.x));
    o.y = f2bf(w0 * bf2f(a.y) + w1 * bf2f(c.y) + w2 * bf2f(e.y));
    o.z = f2bf(w0 * bf2f(a.z) + w1 * bf2f(c.z) + w2 * bf2f(e.z));
    o.w = f2bf(w0 * bf2f(a.w) + w1 * bf2f(c.w) + w2 * bf2f(e.w));
    int nn = blockIdx.x * 16 + p;
    *((ushort4*)(np + ((size_t)b * N_ + nn) * 384 + 128) + lane) = o;
  }
}

// ---------------- bf16 GEMM (m97 structure, BK=64): C[M][256] = A[M][K] * W[256][K]^T
// grid (M/128, 256/128), block 256 (4 waves, 2x2), BK=64, 16x16x32 bf16 MFMA.
// BK=128 regressed (R12, m132-consistent); BK=64 pinned.
__global__ __launch_bounds__(256) void gemm_bt(const unsigned short* __restrict__ A,
                                               const unsigned short* __restrict__ Bw,
                                               float* __restrict__ C, int K) {
  __shared__ unsigned short As[128 * 64];
  __shared__ unsigned short Bs[128 * 64];
  int tid = threadIdx.x;
  int lane = tid & 63, wave = tid >> 6;
  int wr = wave >> 1, wc = wave & 1;
  size_t m0 = (size_t)blockIdx.x * 128;
  int n0 = blockIdx.y * 128;
  int lr = lane & 15, lk = lane >> 4;
  f32x4 acc[4][4] = {};

  for (int kt = 0; kt < K; kt += 64) {
#pragma unroll
    for (int i = 0; i < 4; ++i) {
      int ch = i * 256 + tid;
      int row = ch >> 3;
      int col = (ch & 7) * 8;
      __builtin_amdgcn_global_load_lds(
          (const __attribute__((address_space(1))) void*)(A + (m0 + row) * K + kt + col),
          (__attribute__((address_space(3))) void*)(As + ch * 8), 16, 0, 0);
    }
#pragma unroll
    for (int i = 0; i < 4; ++i) {
      int ch = i * 256 + tid;
      int row = ch >> 3;
      int col = (ch & 7) * 8;
      __builtin_amdgcn_global_load_lds(
          (const __attribute__((address_space(1))) void*)(Bw + (size_t)(n0 + row) * K + kt + col),
          (__attribute__((address_space(3))) void*)(Bs + ch * 8), 16, 0, 0);
    }
    __syncthreads();

    bf16x8 af[4][2], bf[4][2];
#pragma unroll
    for (int m = 0; m < 4; ++m)
#pragma unroll
      for (int kk = 0; kk < 2; ++kk)
        af[m][kk] = *(const bf16x8*)(As + (wr * 64 + m * 16 + lr) * 64 + kk * 32 + lk * 8);
#pragma unroll
    for (int nn = 0; nn < 4; ++nn)
#pragma unroll
      for (int kk = 0; kk < 2; ++kk)
        bf[nn][kk] = *(const bf16x8*)(Bs + (wc * 64 + nn * 16 + lr) * 64 + kk * 32 + lk * 8);

#pragma unroll
    for (int m = 0; m < 4; ++m)
#pragma unroll
      for (int nn = 0; nn < 4; ++nn)
#pragma unroll
        for (int kk = 0; kk < 2; ++kk)
          acc[m][nn] = __builtin_amdgcn_mfma_f32_16x16x32_bf16(af[m][kk], bf[nn][kk], acc[m][nn], 0, 0, 0);
    __syncthreads();
  }

  // C/D layout (m89): col = lane&15, row = (lane>>4)*4 + j
#pragma unroll
  for (int m = 0; m < 4; ++m) {
    size_t row = m0 + wr * 64 + m * 16 + lk * 4;
#pragma unroll
    for (int j = 0; j < 4; ++j) {
      float* cr = C + (row + j) * 256 + n0 + wc * 64 + lr;
#pragma unroll
      for (int nn = 0; nn < 4; ++nn)
        cr[nn * 16] = acc[m][nn][j];
    }
  }
}

// ---------------- per-channel sum / sumsq over rows of X [M][256] ----------------
// grid 128 (256 rows each), block 256 = channel. Grid sweep R11/R13/R14:
// @128=160.6 total, @256=166, @512=184 -> atomic same-address serialization
// (~50cyc/add) dominates; 128 blocks/address is the measured optimum. PINNED.
__global__ void col_stats(const float* __restrict__ X, float* __restrict__ sums) {
  int c = threadIdx.x;
  size_t r0 = (size_t)blockIdx.x * 256;
  float s0 = 0, s1 = 0, s2 = 0, s3 = 0, q0 = 0, q1 = 0, q2 = 0, q3 = 0;
  for (int r = 0; r < 256; r += 4) {
    float v0 = X[(r0 + r + 0) * 256 + c];
    float v1 = X[(r0 + r + 1) * 256 + c];
    float v2 = X[(r0 + r + 2) * 256 + c];
    float v3 = X[(r0 + r + 3) * 256 + c];
    s0 += v0; q0 += v0 * v0;
    s1 += v1; q1 += v1 * v1;
    s2 += v2; q2 += v2 * v2;
    s3 += v3; q3 += v3 * v3;
  }
  atomicAdd(&sums[c], s0 + s1 + s2 + s3);
  atomicAdd(&sums[256 + c], q0 + q1 + q2 + q3);
}

// ---------------- BN (train) + ReLU + cast bf16: Y[M][256] ----------------
__global__ void bn_relu_kernel(const float* __restrict__ X, const float* __restrict__ sums,
                               const float* __restrict__ g, const float* __restrict__ be,
                               unsigned short* __restrict__ Y) {
  __shared__ float sc[256], sh[256];
  int t = threadIdx.x;
  {
    float s = sums[t], q = sums[256 + t];
    float m = s * (1.0f / 32768.0f);
    float v = q * (1.0f / 32768.0f) - m * m;
    float scale = g[t] * rsqrtf(v + 1e-5f);
    sc[t] = scale; sh[t] = be[t] - m * scale;
  }
  __syncthreads();
  const float4* X4 = (const float4*)X;
  ushort4* Y4 = (ushort4*)Y;
  for (size_t i = (size_t)blockIdx.x * 256 + t; i < (size_t)M_ * 64; i += 2048 * 256) {
    float4 x = X4[i];
    int c0 = (int)((i * 4) & 255);
    ushort4 o;
    o.x = f2bf(fmaxf(x.x * sc[c0 + 0] + sh[c0 + 0], 0.f));
    o.y = f2bf(fmaxf(x.y * sc[c0 + 1] + sh[c0 + 1], 0.f));
    o.z = f2bf(fmaxf(x.z * sc[c0 + 2] + sh[c0 + 2], 0.f));
    o.w = f2bf(fmaxf(x.w * sc[c0 + 3] + sh[c0 + 3], 0.f));
    Y4[i] = o;
  }
}

// ---------------- final: out[b][o][n] = relu(x + BN2(z)), tiled transpose ----------------
__global__ void final_kernel(const float* __restrict__ Z, const unsigned short* __restrict__ Xb,
                             const float* __restrict__ sums2, const float* __restrict__ g2,
                             const float* __restrict__ be2, float* __restrict__ out) {
  __shared__ float sc[64], sh[64];
  __shared__ float tile[64 * 65];
  int t = threadIdx.x;
  int o0 = blockIdx.y * 64;
  if (t < 64) {
    int c = o0 + t;
    float s = sums2[c], q = sums2[256 + c];
    float m = s * (1.0f / 32768.0f);
    float v = q * (1.0f / 32768.0f) - m * m;
    float scale = g2[c] * rsqrtf(v + 1e-5f);
    sc[t] = scale; sh[t] = be2[c] - m * scale;
  }
  __syncthreads();
  size_t m0 = (size_t)blockIdx.x * 64;
  int rl = t >> 4, cq = t & 15;
#pragma unroll
  for (int rr = 0; rr < 4; ++rr) {
    int row = rr * 16 + rl;
    size_t base = (m0 + row) * 256 + o0 + cq * 4;
    float4 z = *(const float4*)(Z + base);
    ushort4 x = *(const ushort4*)(Xb + base);
    int c = cq * 4;
    tile[row * 65 + c + 0] = fmaxf(z.x * sc[c + 0] + sh[c + 0] + bf2f(x.x), 0.f);
    tile[row * 65 + c + 1] = fmaxf(z.y * sc[c + 1] + sh[c + 1] + bf2f(x.y), 0.f);
    tile[row * 65 + c + 2] = fmaxf(z.z * sc[c + 2] + sh[c + 2] + bf2f(x.z), 0.f);
    tile[row * 65 + c + 3] = fmaxf(z.w * sc[c + 3] + sh[c + 3] + bf2f(x.w), 0.f);
  }
  __syncthreads();
  int b = (int)(m0 >> 13);
  int nbase = (int)(m0 & 8191);
  int orow = t >> 4, nq = t & 15;
#pragma unroll
  for (int ov = 0; ov < 4; ++ov) {
    int o = ov * 16 + orow;
    float4 v;
    v.x = tile[(nq * 4 + 0) * 65 + o];
    v.y = tile[(nq * 4 + 1) * 65 + o];
    v.z = tile[(nq * 4 + 2) * 65 + o];
    v.w = tile[(nq * 4 + 3) * 65 + o];
    *(float4*)(out + ((size_t)(b * 256 + o0 + o)) * 8192 + nbase + nq * 4) = v;
  }
}

extern "C" void kernel_launch(void* const* d_in, const int* in_sizes, int n_in,
                              void* d_out, int out_size, void* d_ws, size_t ws_size,
                              hipStream_t stream) {
  const float* xyz1    = (const float*)d_in[0];
  const float* xyz2    = (const float*)d_in[1];
  const float* points1 = (const float*)d_in[2];
  const float* points2 = (const float*)d_in[3];
  const float* W_fuse  = (const float*)d_in[4];
  // biases d_in[5], d_in[9], d_in[13] cancel exactly under training-mode BN
  const float* g_fuse  = (const float*)d_in[6];
  const float* be_fuse = (const float*)d_in[7];
  const float* W1      = (const float*)d_in[8];
  const float* g1      = (const float*)d_in[10];
  const float* be1     = (const float*)d_in[11];
  const float* W2      = (const float*)d_in[12];
  const float* g2      = (const float*)d_in[14];
  const float* be2     = (const float*)d_in[15];
  float* out = (float*)d_out;

  char* ws = (char*)d_ws;
  float* lin = (float*)ws;                   ws += (size_t)M_ * 256 * 4;   // 33.5 MB, reused 3x
  unsigned short* xb = (unsigned short*)ws;  ws += (size_t)M_ * 256 * 2;   // 16.8 MB
  unsigned short* np = (unsigned short*)ws;  ws += (size_t)M_ * 384 * 2;   // 25.2 MB (yb aliases np)
  unsigned short* yb = np;                                                  // np dead after fuse GEMM
  unsigned short* p2t = (unsigned short*)ws; ws += (size_t)B_ * S_ * 256 * 2; // 4.2 MB
  unsigned short* wb = (unsigned short*)ws;  ws += 229376 * 2;
  float* stats = (float*)ws;                 // 6*256 floats

  // prologue: weights pack + stats zero (1 dispatch), both transposes (1 dispatch)
  pack_weights<<<896, 256, 0, stream>>>(W_fuse, W1, W2, wb, stats);
  transpose_both<<<dim3(1536, 1, B_), dim3(32, 8), 0, stream>>>(points1, np, points2, p2t);
  // 3-NN interp -> new_points[:, 128:384]
  knn_interp_kernel<<<dim3(N_ / 16, B_), 256, 0, stream>>>(xyz1, xyz2, p2t, np);
  // fuse layer
  gemm_bt<<<dim3(M_ / 128, 2), 256, 0, stream>>>(np, wb, lin, 384);
  col_stats<<<128, 256, 0, stream>>>(lin, stats);
  bn_relu_kernel<<<2048, 256, 0, stream>>>(lin, stats, g_fuse, be_fuse, xb);
  // residual block conv1
  gemm_bt<<<dim3(M_ / 128, 2), 256, 0, stream>>>(xb, wb + 98304, lin, 256);
  col_stats<<<128, 256, 0, stream>>>(lin, stats + 512);
  bn_relu_kernel<<<2048, 256, 0, stream>>>(lin, stats + 512, g1, be1, yb);
  // residual block conv2
  gemm_bt<<<dim3(M_ / 128, 2), 256, 0, stream>>>(yb, wb + 163840, lin, 256);
  col_stats<<<128, 256, 0, stream>>>(lin, stats + 1024);
  // BN2 + residual + relu + transpose to [B][256][N]
  final_kernel<<<dim3(M_ / 64, 4), 256, 0, stream>>>(lin, xb, stats + 1024, g2, be2, out);
}

// Round 17
// 153.345 us; speedup vs baseline: 1.2209x; 1.0271x over previous
//
#include <hip/hip_runtime.h>
#include <cstdint>
#include <cstddef>

#define B_ 4
#define N_ 8192
#define S_ 2048
#define M_ 32768   // B_*N_

typedef short bf16x8 __attribute__((ext_vector_type(8)));
typedef float f32x4 __attribute__((ext_vector_type(4)));

__device__ __forceinline__ float bf2f(unsigned short u) {
  union { unsigned int i; float f; } v; v.i = ((unsigned int)u) << 16; return v.f;
}
__device__ __forceinline__ unsigned short f2bf(float f) {
  union { float f; unsigned int i; } v; v.f = f;
  return (unsigned short)((v.i + 0x7FFFu + ((v.i >> 16) & 1u)) >> 16);
}

// ---------------- pack weights f32 -> bf16 + zero stats (fused memset) ----------------
// stats layout: 3 layers x 4 shards x 512 floats = 6144 floats.
__global__ void pack_weights(const float* __restrict__ Wf, const float* __restrict__ W1,
                             const float* __restrict__ W2, unsigned short* __restrict__ out,
                             float* __restrict__ stats) {
  int i = blockIdx.x * 256 + threadIdx.x;   // grid covers exactly 229376
  if (blockIdx.x == 0) {
#pragma unroll
    for (int k = 0; k < 24; ++k) stats[k * 256 + threadIdx.x] = 0.f;
  }
  float v;
  if (i < 98304)       v = Wf[i];
  else if (i < 163840) v = W1[i - 98304];
  else                 v = W2[i - 163840];
  out[i] = f2bf(v);
}

// ---------------- combined tiled transposes (both jobs, one dispatch) ----------------
// grid dim3(1536, 1, B_), block (32,8).
// bx < 1024: points1 [B][128][8192] f32 -> np rows ld=384 coff=0   (256 x 4 tiles)
// bx >= 1024: points2 [B][256][2048] f32 -> p2t rows ld=256 coff=0 ( 64 x 8 tiles)
__global__ void transpose_both(const float* __restrict__ points1, unsigned short* __restrict__ np,
                               const float* __restrict__ points2, unsigned short* __restrict__ p2t) {
  __shared__ float t[32][33];
  int bx = blockIdx.x;
  int b = blockIdx.z;
  const float* src; unsigned short* dst;
  int C, Nsp, ldo, n0, c0;
  if (bx < 1024) {
    src = points1; dst = np; C = 128; Nsp = 8192; ldo = 384;
    n0 = (bx & 255) * 32; c0 = (bx >> 8) * 32;
  } else {
    int j = bx - 1024;
    src = points2; dst = p2t; C = 256; Nsp = 2048; ldo = 256;
    n0 = (j & 63) * 32; c0 = (j >> 6) * 32;
  }
  int x = threadIdx.x, y = threadIdx.y;
  const float* s = src + ((size_t)b * C + c0) * Nsp + n0;
#pragma unroll
  for (int k = 0; k < 4; ++k)
    t[y + k * 8][x] = s[(size_t)(y + k * 8) * Nsp + x];
  __syncthreads();
#pragma unroll
  for (int k = 0; k < 4; ++k) {
    int n = n0 + y + k * 8;
    dst[((size_t)b * Nsp + n) * ldo + c0 + x] = f2bf(t[x][y + k * 8]);
  }
}

// lexicographic (d, idx) strict less-than: matches top_k's stable tie-break
__device__ __forceinline__ bool lexlt(float da, int ia, float db, int ib) {
  return (da < db) || (da == db && ia < ib);
}

// ---------------- 3-NN + inverse-distance interpolation (R11 version, 40.7us, PINNED) ----
// grid (N_/16, B_), block 256 (4 waves, 16 queries/block). 16 lanes per query,
// each scans 128 candidates ranked by key = |c|^2 - 2 p.c. Candidates staged in
// two 16 KB LDS chunks so 8 blocks/CU fit (8192 waves total -- TLP is the
// latency-hiding mechanism; both lower-wave restructures regressed, R7/R15).
__global__ __launch_bounds__(256, 8) void knn_interp_kernel(
    const float* __restrict__ xyz1, const float* __restrict__ xyz2,
    const unsigned short* __restrict__ p2t, unsigned short* __restrict__ np) {
  __shared__ float4 sp[1024];        // 16 KB candidate chunk (xyz, |c|^2)
  __shared__ float sw[16][3];
  __shared__ int   sidx[16][3];
  int t = threadIdx.x;
  int b = blockIdx.y;
  const float* xb = xyz2 + (size_t)b * S_ * 3;

  int lane = t & 63, wave = t >> 6;
  int sub = lane & 15;               // which 1/16 of candidate set
  int pib = wave * 4 + (lane >> 4);  // point in block (0..15)
  int n = blockIdx.x * 16 + pib;
  const float* q = xyz1 + ((size_t)b * N_ + n) * 3;
  float px = q[0], py = q[1], pz = q[2];
  float nx = -2.f * px, ny = -2.f * py, nz = -2.f * pz;
  float aa = fmaf(px, px, fmaf(py, py, pz * pz));

  float d0 = 1e30f, d1 = 1e30f, d2 = 1e30f;
  int i0 = S_, i1 = S_, i2 = S_;

  for (int chunk = 0; chunk < 2; ++chunk) {
    __syncthreads();                 // previous chunk's readers done
    for (int i = t; i < 1024; i += 256) {
      int c = chunk * 1024 + i;
      float cx = xb[3 * c], cy = xb[3 * c + 1], cz = xb[3 * c + 2];
      sp[i] = make_float4(cx, cy, cz, fmaf(cx, cx, fmaf(cy, cy, cz * cz)));
    }
    __syncthreads();
    int sbase = chunk * 1024;
#pragma unroll 8
    for (int i = 0; i < 64; ++i) {
      int sl = i * 16 + sub;
      float4 c = sp[sl];
      float d = fmaf(nx, c.x, fmaf(ny, c.y, fmaf(nz, c.z, c.w)));  // |c|^2 - 2 p.c
      int s = sbase + sl;
      // scan visits indices in increasing order, so strict < keeps lower index on ties
      bool b0 = d < d0, b1 = d < d1, b2 = d < d2;
      i2 = b1 ? i1 : (b2 ? s : i2);
      i1 = b0 ? i0 : (b1 ? s : i1);
      i0 = b0 ? s : i0;
      // value path: identical results to the cndmask chain, 3 ops instead of 5
      float nd1 = __builtin_amdgcn_fmed3f(d, d0, d1);
      float nd2 = __builtin_amdgcn_fmed3f(d, d1, d2);
      d0 = fminf(d0, d);
      d1 = nd1; d2 = nd2;
    }
  }

  // merge sorted triples across the 16 lanes of each query group.
  // k-th smallest of union = min_{i+j=k} max(a_i, b_j)  (order-statistic identity)
#pragma unroll
  for (int m = 1; m <= 8; m <<= 1) {
    float e0 = __shfl_xor(d0, m, 64), e1 = __shfl_xor(d1, m, 64), e2 = __shfl_xor(d2, m, 64);
    int   j0 = __shfl_xor(i0, m, 64), j1 = __shfl_xor(i1, m, 64), j2 = __shfl_xor(i2, m, 64);
    bool l0 = lexlt(d0, i0, e0, j0);
    float m0d = l0 ? d0 : e0;  int m0i = l0 ? i0 : j0;   // min(a0,b0)
    float x0d = l0 ? e0 : d0;  int x0i = l0 ? j0 : i0;   // max(a0,b0)
    bool l11 = lexlt(d1, i1, e1, j1);
    float n1d = l11 ? d1 : e1; int n1i = l11 ? i1 : j1;  // min(a1,b1)
    bool l1 = lexlt(n1d, n1i, x0d, x0i);
    float m1d = l1 ? n1d : x0d; int m1i = l1 ? n1i : x0i;        // 2nd smallest
    bool l01 = lexlt(d0, i0, e1, j1);
    float p1d = l01 ? e1 : d0; int p1i = l01 ? j1 : i0;  // max(a0,b1)
    bool l10 = lexlt(d1, i1, e0, j0);
    float p2d = l10 ? e0 : d1; int p2i = l10 ? j0 : i1;  // max(a1,b0)
    bool lp = lexlt(p1d, p1i, p2d, p2i);
    float p3d = lp ? p1d : p2d; int p3i = lp ? p1i : p2i;
    bool l22 = lexlt(d2, i2, e2, j2);
    float p4d = l22 ? d2 : e2; int p4i = l22 ? i2 : j2;  // min(a2,b2)
    bool l2 = lexlt(p3d, p3i, p4d, p4i);
    float m2d = l2 ? p3d : p4d; int m2i = l2 ? p3i : p4i;        // 3rd smallest
    d0 = m0d; i0 = m0i; d1 = m1d; i1 = m1i; d2 = m2d; i2 = m2i;
  }

  if (sub == 0) {
    float t0 = aa + d0, t1 = aa + d1, t2 = aa + d2;   // true squared distances
    float r0 = 1.f / (t0 + 1e-8f), r1 = 1.f / (t1 + 1e-8f), r2 = 1.f / (t2 + 1e-8f);
    float rs = 1.f / (r0 + r1 + r2);
    sw[pib][0] = r0 * rs; sw[pib][1] = r1 * rs; sw[pib][2] = r2 * rs;
    sidx[pib][0] = i0; sidx[pib][1] = i1; sidx[pib][2] = i2;
  }
  __syncthreads();

  // gather + weighted sum -> new_points[:, 128:384]
  for (int p = wave; p < 16; p += 4) {
    float w0 = sw[p][0], w1 = sw[p][1], w2 = sw[p][2];
    const ushort4* g0 = (const ushort4*)(p2t + ((size_t)b * S_ + sidx[p][0]) * 256) + lane;
    const ushort4* g1 = (const ushort4*)(p2t + ((size_t)b * S_ + sidx[p][1]) * 256) + lane;
    const ushort4* g2 = (const ushort4*)(p2t + ((size_t)b * S_ + sidx[p][2]) * 256) + lane;
    ushort4 a = *g0, c = *g1, e = *g2;
    ushort4 o;
    o.x = f2bf(w0 * bf2f(a.x) + w1 * bf2f(c.x) + w2 * bf2f(e.x));
    o.y = f2bf(w0 * bf2f(a.y) + w1 * bf2f(c.y) + w2 * bf2f(e.y));
    o.z = f2bf(w0 * bf2f(a.z) + w1 * bf2f(c.z) + w2 * bf2f(e.z));
    o.w = f2bf(w0 * bf2f(a.w) + w1 * bf2f(c.w) + w2 * bf2f(e.w));
    int nn = blockIdx.x * 16 + p;
    *((ushort4*)(np + ((size_t)b * N_ + nn) * 384 + 128) + lane) = o;
  }
}

// ---------------- bf16 GEMM (m97 structure, BK=64): C[M][256] = A[M][K] * W[256][K]^T
// grid (M/128, 256/128), block 256 (4 waves, 2x2), BK=64, 16x16x32 bf16 MFMA.
// BK=128 regressed (R12, m132-consistent); BK=64 pinned.
__global__ __launch_bounds__(256) void gemm_bt(const unsigned short* __restrict__ A,
                                               const unsigned short* __restrict__ Bw,
                                               float* __restrict__ C, int K) {
  __shared__ unsigned short As[128 * 64];
  __shared__ unsigned short Bs[128 * 64];
  int tid = threadIdx.x;
  int lane = tid & 63, wave = tid >> 6;
  int wr = wave >> 1, wc = wave & 1;
  size_t m0 = (size_t)blockIdx.x * 128;
  int n0 = blockIdx.y * 128;
  int lr = lane & 15, lk = lane >> 4;
  f32x4 acc[4][4] = {};

  for (int kt = 0; kt < K; kt += 64) {
#pragma unroll
    for (int i = 0; i < 4; ++i) {
      int ch = i * 256 + tid;
      int row = ch >> 3;
      int col = (ch & 7) * 8;
      __builtin_amdgcn_global_load_lds(
          (const __attribute__((address_space(1))) void*)(A + (m0 + row) * K + kt + col),
          (__attribute__((address_space(3))) void*)(As + ch * 8), 16, 0, 0);
    }
#pragma unroll
    for (int i = 0; i < 4; ++i) {
      int ch = i * 256 + tid;
      int row = ch >> 3;
      int col = (ch & 7) * 8;
      __builtin_amdgcn_global_load_lds(
          (const __attribute__((address_space(1))) void*)(Bw + (size_t)(n0 + row) * K + kt + col),
          (__attribute__((address_space(3))) void*)(Bs + ch * 8), 16, 0, 0);
    }
    __syncthreads();

    bf16x8 af[4][2], bf[4][2];
#pragma unroll
    for (int m = 0; m < 4; ++m)
#pragma unroll
      for (int kk = 0; kk < 2; ++kk)
        af[m][kk] = *(const bf16x8*)(As + (wr * 64 + m * 16 + lr) * 64 + kk * 32 + lk * 8);
#pragma unroll
    for (int nn = 0; nn < 4; ++nn)
#pragma unroll
      for (int kk = 0; kk < 2; ++kk)
        bf[nn][kk] = *(const bf16x8*)(Bs + (wc * 64 + nn * 16 + lr) * 64 + kk * 32 + lk * 8);

#pragma unroll
    for (int m = 0; m < 4; ++m)
#pragma unroll
      for (int nn = 0; nn < 4; ++nn)
#pragma unroll
        for (int kk = 0; kk < 2; ++kk)
          acc[m][nn] = __builtin_amdgcn_mfma_f32_16x16x32_bf16(af[m][kk], bf[nn][kk], acc[m][nn], 0, 0, 0);
    __syncthreads();
  }

  // C/D layout (m89): col = lane&15, row = (lane>>4)*4 + j
#pragma unroll
  for (int m = 0; m < 4; ++m) {
    size_t row = m0 + wr * 64 + m * 16 + lk * 4;
#pragma unroll
    for (int j = 0; j < 4; ++j) {
      float* cr = C + (row + j) * 256 + n0 + wc * 64 + lr;
#pragma unroll
      for (int nn = 0; nn < 4; ++nn)
        cr[nn * 16] = acc[m][nn][j];
    }
  }
}

// ---------------- per-channel sum / sumsq over rows of X [M][256] ----------------
// grid 128 (256 rows each), block 256 = channel; block b adds into shard b&3.
// Same-address atomic serialization ~34cyc/add (R11/R13/R14 sweep); 4 shards cut
// the per-address tail 128 -> 32 adds. sums layout: 4 shards x [sum 256 | sumsq 256].
__global__ void col_stats(const float* __restrict__ X, float* __restrict__ sums) {
  int c = threadIdx.x;
  size_t r0 = (size_t)blockIdx.x * 256;
  float s0 = 0, s1 = 0, s2 = 0, s3 = 0, q0 = 0, q1 = 0, q2 = 0, q3 = 0;
  for (int r = 0; r < 256; r += 4) {
    float v0 = X[(r0 + r + 0) * 256 + c];
    float v1 = X[(r0 + r + 1) * 256 + c];
    float v2 = X[(r0 + r + 2) * 256 + c];
    float v3 = X[(r0 + r + 3) * 256 + c];
    s0 += v0; q0 += v0 * v0;
    s1 += v1; q1 += v1 * v1;
    s2 += v2; q2 += v2 * v2;
    s3 += v3; q3 += v3 * v3;
  }
  float* sh = sums + (blockIdx.x & 3) * 512;
  atomicAdd(&sh[c], s0 + s1 + s2 + s3);
  atomicAdd(&sh[256 + c], q0 + q1 + q2 + q3);
}

// ---------------- BN (train) + ReLU + cast bf16: Y[M][256] ----------------
__global__ void bn_relu_kernel(const float* __restrict__ X, const float* __restrict__ sums,
                               const float* __restrict__ g, const float* __restrict__ be,
                               unsigned short* __restrict__ Y) {
  __shared__ float sc[256], sh[256];
  int t = threadIdx.x;
  {
    float s = sums[t] + sums[512 + t] + sums[1024 + t] + sums[1536 + t];
    float q = sums[256 + t] + sums[768 + t] + sums[1280 + t] + sums[1792 + t];
    float m = s * (1.0f / 32768.0f);
    float v = q * (1.0f / 32768.0f) - m * m;
    float scale = g[t] * rsqrtf(v + 1e-5f);
    sc[t] = scale; sh[t] = be[t] - m * scale;
  }
  __syncthreads();
  const float4* X4 = (const float4*)X;
  ushort4* Y4 = (ushort4*)Y;
  for (size_t i = (size_t)blockIdx.x * 256 + t; i < (size_t)M_ * 64; i += 2048 * 256) {
    float4 x = X4[i];
    int c0 = (int)((i * 4) & 255);
    ushort4 o;
    o.x = f2bf(fmaxf(x.x * sc[c0 + 0] + sh[c0 + 0], 0.f));
    o.y = f2bf(fmaxf(x.y * sc[c0 + 1] + sh[c0 + 1], 0.f));
    o.z = f2bf(fmaxf(x.z * sc[c0 + 2] + sh[c0 + 2], 0.f));
    o.w = f2bf(fmaxf(x.w * sc[c0 + 3] + sh[c0 + 3], 0.f));
    Y4[i] = o;
  }
}

// ---------------- final: out[b][o][n] = relu(x + BN2(z)), tiled transpose ----------------
__global__ void final_kernel(const float* __restrict__ Z, const unsigned short* __restrict__ Xb,
                             const float* __restrict__ sums2, const float* __restrict__ g2,
                             const float* __restrict__ be2, float* __restrict__ out) {
  __shared__ float sc[64], sh[64];
  __shared__ float tile[64 * 65];
  int t = threadIdx.x;
  int o0 = blockIdx.y * 64;
  if (t < 64) {
    int c = o0 + t;
    float s = sums2[c] + sums2[512 + c] + sums2[1024 + c] + sums2[1536 + c];
    float q = sums2[256 + c] + sums2[768 + c] + sums2[1280 + c] + sums2[1792 + c];
    float m = s * (1.0f / 32768.0f);
    float v = q * (1.0f / 32768.0f) - m * m;
    float scale = g2[c] * rsqrtf(v + 1e-5f);
    sc[t] = scale; sh[t] = be2[c] - m * scale;
  }
  __syncthreads();
  size_t m0 = (size_t)blockIdx.x * 64;
  int rl = t >> 4, cq = t & 15;
#pragma unroll
  for (int rr = 0; rr < 4; ++rr) {
    int row = rr * 16 + rl;
    size_t base = (m0 + row) * 256 + o0 + cq * 4;
    float4 z = *(const float4*)(Z + base);
    ushort4 x = *(const ushort4*)(Xb + base);
    int c = cq * 4;
    tile[row * 65 + c + 0] = fmaxf(z.x * sc[c + 0] + sh[c + 0] + bf2f(x.x), 0.f);
    tile[row * 65 + c + 1] = fmaxf(z.y * sc[c + 1] + sh[c + 1] + bf2f(x.y), 0.f);
    tile[row * 65 + c + 2] = fmaxf(z.z * sc[c + 2] + sh[c + 2] + bf2f(x.z), 0.f);
    tile[row * 65 + c + 3] = fmaxf(z.w * sc[c + 3] + sh[c + 3] + bf2f(x.w), 0.f);
  }
  __syncthreads();
  int b = (int)(m0 >> 13);
  int nbase = (int)(m0 & 8191);
  int orow = t >> 4, nq = t & 15;
#pragma unroll
  for (int ov = 0; ov < 4; ++ov) {
    int o = ov * 16 + orow;
    float4 v;
    v.x = tile[(nq * 4 + 0) * 65 + o];
    v.y = tile[(nq * 4 + 1) * 65 + o];
    v.z = tile[(nq * 4 + 2) * 65 + o];
    v.w = tile[(nq * 4 + 3) * 65 + o];
    *(float4*)(out + ((size_t)(b * 256 + o0 + o)) * 8192 + nbase + nq * 4) = v;
  }
}

extern "C" void kernel_launch(void* const* d_in, const int* in_sizes, int n_in,
                              void* d_out, int out_size, void* d_ws, size_t ws_size,
                              hipStream_t stream) {
  const float* xyz1    = (const float*)d_in[0];
  const float* xyz2    = (const float*)d_in[1];
  const float* points1 = (const float*)d_in[2];
  const float* points2 = (const float*)d_in[3];
  const float* W_fuse  = (const float*)d_in[4];
  // biases d_in[5], d_in[9], d_in[13] cancel exactly under training-mode BN
  const float* g_fuse  = (const float*)d_in[6];
  const float* be_fuse = (const float*)d_in[7];
  const float* W1      = (const float*)d_in[8];
  const float* g1      = (const float*)d_in[10];
  const float* be1     = (const float*)d_in[11];
  const float* W2      = (const float*)d_in[12];
  const float* g2      = (const float*)d_in[14];
  const float* be2     = (const float*)d_in[15];
  float* out = (float*)d_out;

  char* ws = (char*)d_ws;
  float* lin = (float*)ws;                   ws += (size_t)M_ * 256 * 4;   // 33.5 MB, reused 3x
  unsigned short* xb = (unsigned short*)ws;  ws += (size_t)M_ * 256 * 2;   // 16.8 MB
  unsigned short* np = (unsigned short*)ws;  ws += (size_t)M_ * 384 * 2;   // 25.2 MB (yb aliases np)
  unsigned short* yb = np;                                                  // np dead after fuse GEMM
  unsigned short* p2t = (unsigned short*)ws; ws += (size_t)B_ * S_ * 256 * 2; // 4.2 MB
  unsigned short* wb = (unsigned short*)ws;  ws += 229376 * 2;
  float* stats = (float*)ws;                 // 3 layers x 4 shards x 512 = 6144 floats

  // prologue: weights pack + stats zero (1 dispatch), both transposes (1 dispatch)
  pack_weights<<<896, 256, 0, stream>>>(W_fuse, W1, W2, wb, stats);
  transpose_both<<<dim3(1536, 1, B_), dim3(32, 8), 0, stream>>>(points1, np, points2, p2t);
  // 3-NN interp -> new_points[:, 128:384]
  knn_interp_kernel<<<dim3(N_ / 16, B_), 256, 0, stream>>>(xyz1, xyz2, p2t, np);
  // fuse layer
  gemm_bt<<<dim3(M_ / 128, 2), 256, 0, stream>>>(np, wb, lin, 384);
  col_stats<<<128, 256, 0, stream>>>(lin, stats);
  bn_relu_kernel<<<2048, 256, 0, stream>>>(lin, stats, g_fuse, be_fuse, xb);
  // residual block conv1
  gemm_bt<<<dim3(M_ / 128, 2), 256, 0, stream>>>(xb, wb + 98304, lin, 256);
  col_stats<<<128, 256, 0, stream>>>(lin, stats + 2048);
  bn_relu_kernel<<<2048, 256, 0, stream>>>(lin, stats + 2048, g1, be1, yb);
  // residual block conv2
  gemm_bt<<<dim3(M_ / 128, 2), 256, 0, stream>>>(yb, wb + 163840, lin, 256);
  col_stats<<<128, 256, 0, stream>>>(lin, stats + 4096);
  // BN2 + residual + relu + transpose to [B][256][N]
  final_kernel<<<dim3(M_ / 64, 4), 256, 0, stream>>>(lin, xb, stats + 4096, g2, be2, out);
}

// Round 19
// 152.858 us; speedup vs baseline: 1.2248x; 1.0032x over previous
//
#include <hip/hip_runtime.h>
#include <cstdint>
#include <cstddef>

#define B_ 4
#define N_ 8192
#define S_ 2048
#define M_ 32768   // B_*N_

typedef short bf16x8 __attribute__((ext_vector_type(8)));
typedef float f32x4 __attribute__((ext_vector_type(4)));

__device__ __forceinline__ float bf2f(unsigned short u) {
  union { unsigned int i; float f; } v; v.i = ((unsigned int)u) << 16; return v.f;
}
__device__ __forceinline__ unsigned short f2bf(float f) {
  union { float f; unsigned int i; } v; v.f = f;
  return (unsigned short)((v.i + 0x7FFFu + ((v.i >> 16) & 1u)) >> 16);
}

// ---------------- pack weights f32 -> bf16 + zero stats (fused memset) ----------------
// stats layout: 3 layers x 8 shards x 512 floats = 12288 floats (48 x 256).
__global__ void pack_weights(const float* __restrict__ Wf, const float* __restrict__ W1,
                             const float* __restrict__ W2, unsigned short* __restrict__ out,
                             float* __restrict__ stats) {
  int i = blockIdx.x * 256 + threadIdx.x;   // grid covers exactly 229376
  if (blockIdx.x == 0) {
#pragma unroll
    for (int k = 0; k < 48; ++k) stats[k * 256 + threadIdx.x] = 0.f;
  }
  float v;
  if (i < 98304)       v = Wf[i];
  else if (i < 163840) v = W1[i - 98304];
  else                 v = W2[i - 163840];
  out[i] = f2bf(v);
}

// ---------------- combined tiled transposes (both jobs, one dispatch) ----------------
__global__ void transpose_both(const float* __restrict__ points1, unsigned short* __restrict__ np,
                               const float* __restrict__ points2, unsigned short* __restrict__ p2t) {
  __shared__ float t[32][33];
  int bx = blockIdx.x;
  int b = blockIdx.z;
  const float* src; unsigned short* dst;
  int C, Nsp, ldo, n0, c0;
  if (bx < 1024) {
    src = points1; dst = np; C = 128; Nsp = 8192; ldo = 384;
    n0 = (bx & 255) * 32; c0 = (bx >> 8) * 32;
  } else {
    int j = bx - 1024;
    src = points2; dst = p2t; C = 256; Nsp = 2048; ldo = 256;
    n0 = (j & 63) * 32; c0 = (j >> 6) * 32;
  }
  int x = threadIdx.x, y = threadIdx.y;
  const float* s = src + ((size_t)b * C + c0) * Nsp + n0;
#pragma unroll
  for (int k = 0; k < 4; ++k)
    t[y + k * 8][x] = s[(size_t)(y + k * 8) * Nsp + x];
  __syncthreads();
#pragma unroll
  for (int k = 0; k < 4; ++k) {
    int n = n0 + y + k * 8;
    dst[((size_t)b * Nsp + n) * ldo + c0 + x] = f2bf(t[x][y + k * 8]);
  }
}

// lexicographic (d, idx) strict less-than: matches top_k's stable tie-break
__device__ __forceinline__ bool lexlt(float da, int ia, float db, int ib) {
  return (da < db) || (da == db && ia < ib);
}

// ---------------- 3-NN + inverse-distance interpolation (R11 version, PINNED) ----------
// grid (N_/16, B_), block 256 (4 waves, 16 queries/block). 16 lanes per query,
// each scans 128 candidates ranked by key = |c|^2 - 2 p.c. Candidates staged in
// two 16 KB LDS chunks so 8 blocks/CU fit (8192 waves; TLP is the latency hider
// -- both lower-wave restructures regressed, R7/R15).
__global__ __launch_bounds__(256, 8) void knn_interp_kernel(
    const float* __restrict__ xyz1, const float* __restrict__ xyz2,
    const unsigned short* __restrict__ p2t, unsigned short* __restrict__ np) {
  __shared__ float4 sp[1024];        // 16 KB candidate chunk (xyz, |c|^2)
  __shared__ float sw[16][3];
  __shared__ int   sidx[16][3];
  int t = threadIdx.x;
  int b = blockIdx.y;
  const float* xb = xyz2 + (size_t)b * S_ * 3;

  int lane = t & 63, wave = t >> 6;
  int sub = lane & 15;               // which 1/16 of candidate set
  int pib = wave * 4 + (lane >> 4);  // point in block (0..15)
  int n = blockIdx.x * 16 + pib;
  const float* q = xyz1 + ((size_t)b * N_ + n) * 3;
  float px = q[0], py = q[1], pz = q[2];
  float nx = -2.f * px, ny = -2.f * py, nz = -2.f * pz;
  float aa = fmaf(px, px, fmaf(py, py, pz * pz));

  float d0 = 1e30f, d1 = 1e30f, d2 = 1e30f;
  int i0 = S_, i1 = S_, i2 = S_;

  for (int chunk = 0; chunk < 2; ++chunk) {
    __syncthreads();                 // previous chunk's readers done
    for (int i = t; i < 1024; i += 256) {
      int c = chunk * 1024 + i;
      float cx = xb[3 * c], cy = xb[3 * c + 1], cz = xb[3 * c + 2];
      sp[i] = make_float4(cx, cy, cz, fmaf(cx, cx, fmaf(cy, cy, cz * cz)));
    }
    __syncthreads();
    int sbase = chunk * 1024;
#pragma unroll 8
    for (int i = 0; i < 64; ++i) {
      int sl = i * 16 + sub;
      float4 c = sp[sl];
      float d = fmaf(nx, c.x, fmaf(ny, c.y, fmaf(nz, c.z, c.w)));  // |c|^2 - 2 p.c
      int s = sbase + sl;
      // scan visits indices in increasing order, so strict < keeps lower index on ties
      bool b0 = d < d0, b1 = d < d1, b2 = d < d2;
      i2 = b1 ? i1 : (b2 ? s : i2);
      i1 = b0 ? i0 : (b1 ? s : i1);
      i0 = b0 ? s : i0;
      // value path: identical results to the cndmask chain, 3 ops instead of 5
      float nd1 = __builtin_amdgcn_fmed3f(d, d0, d1);
      float nd2 = __builtin_amdgcn_fmed3f(d, d1, d2);
      d0 = fminf(d0, d);
      d1 = nd1; d2 = nd2;
    }
  }

  // merge sorted triples across the 16 lanes of each query group.
  // k-th smallest of union = min_{i+j=k} max(a_i, b_j)  (order-statistic identity)
#pragma unroll
  for (int m = 1; m <= 8; m <<= 1) {
    float e0 = __shfl_xor(d0, m, 64), e1 = __shfl_xor(d1, m, 64), e2 = __shfl_xor(d2, m, 64);
    int   j0 = __shfl_xor(i0, m, 64), j1 = __shfl_xor(i1, m, 64), j2 = __shfl_xor(i2, m, 64);
    bool l0 = lexlt(d0, i0, e0, j0);
    float m0d = l0 ? d0 : e0;  int m0i = l0 ? i0 : j0;   // min(a0,b0)
    float x0d = l0 ? e0 : d0;  int x0i = l0 ? j0 : i0;   // max(a0,b0)
    bool l11 = lexlt(d1, i1, e1, j1);
    float n1d = l11 ? d1 : e1; int n1i = l11 ? i1 : j1;  // min(a1,b1)
    bool l1 = lexlt(n1d, n1i, x0d, x0i);
    float m1d = l1 ? n1d : x0d; int m1i = l1 ? n1i : x0i;        // 2nd smallest
    bool l01 = lexlt(d0, i0, e1, j1);
    float p1d = l01 ? e1 : d0; int p1i = l01 ? j1 : i0;  // max(a0,b1)
    bool l10 = lexlt(d1, i1, e0, j0);
    float p2d = l10 ? e0 : d1; int p2i = l10 ? j0 : i1;  // max(a1,b0)
    bool lp = lexlt(p1d, p1i, p2d, p2i);
    float p3d = lp ? p1d : p2d; int p3i = lp ? p1i : p2i;
    bool l22 = lexlt(d2, i2, e2, j2);
    float p4d = l22 ? d2 : e2; int p4i = l22 ? i2 : j2;  // min(a2,b2)
    bool l2 = lexlt(p3d, p3i, p4d, p4i);
    float m2d = l2 ? p3d : p4d; int m2i = l2 ? p3i : p4i;        // 3rd smallest
    d0 = m0d; i0 = m0i; d1 = m1d; i1 = m1i; d2 = m2d; i2 = m2i;
  }

  if (sub == 0) {
    float t0 = aa + d0, t1 = aa + d1, t2 = aa + d2;   // true squared distances
    float r0 = 1.f / (t0 + 1e-8f), r1 = 1.f / (t1 + 1e-8f), r2 = 1.f / (t2 + 1e-8f);
    float rs = 1.f / (r0 + r1 + r2);
    sw[pib][0] = r0 * rs; sw[pib][1] = r1 * rs; sw[pib][2] = r2 * rs;
    sidx[pib][0] = i0; sidx[pib][1] = i1; sidx[pib][2] = i2;
  }
  __syncthreads();

  // gather + weighted sum -> new_points[:, 128:384]
  for (int p = wave; p < 16; p += 4) {
    float w0 = sw[p][0], w1 = sw[p][1], w2 = sw[p][2];
    const ushort4* g0 = (const ushort4*)(p2t + ((size_t)b * S_ + sidx[p][0]) * 256) + lane;
    const ushort4* g1 = (const ushort4*)(p2t + ((size_t)b * S_ + sidx[p][1]) * 256) + lane;
    const ushort4* g2 = (const ushort4*)(p2t + ((size_t)b * S_ + sidx[p][2]) * 256) + lane;
    ushort4 a = *g0, c = *g1, e = *g2;
    ushort4 o;
    o.x = f2bf(w0 * bf2f(a.x) + w1 * bf2f(c.x) + w2 * bf2f(e.x));
    o.y = f2bf(w0 * bf2f(a.y) + w1 * bf2f(c.y) + w2 * bf2f(e.y));
    o.z = f2bf(w0 * bf2f(a.z) + w1 * bf2f(c.z) + w2 * bf2f(e.z));
    o.w = f2bf(w0 * bf2f(a.w) + w1 * bf2f(c.w) + w2 * bf2f(e.w));
    int nn = blockIdx.x * 16 + p;
    *((ushort4*)(np + ((size_t)b * N_ + nn) * 384 + 128) + lane) = o;
  }
}

// ---------------- bf16 GEMM (m97 structure, BK=64, PINNED) ----------------
__global__ __launch_bounds__(256) void gemm_bt(const unsigned short* __restrict__ A,
                                               const unsigned short* __restrict__ Bw,
                                               float* __restrict__ C, int K) {
  __shared__ unsigned short As[128 * 64];
  __shared__ unsigned short Bs[128 * 64];
  int tid = threadIdx.x;
  int lane = tid & 63, wave = tid >> 6;
  int wr = wave >> 1, wc = wave & 1;
  size_t m0 = (size_t)blockIdx.x * 128;
  int n0 = blockIdx.y * 128;
  int lr = lane & 15, lk = lane >> 4;
  f32x4 acc[4][4] = {};

  for (int kt = 0; kt < K; kt += 64) {
#pragma unroll
    for (int i = 0; i < 4; ++i) {
      int ch = i * 256 + tid;
      int row = ch >> 3;
      int col = (ch & 7) * 8;
      __builtin_amdgcn_global_load_lds(
          (const __attribute__((address_space(1))) void*)(A + (m0 + row) * K + kt + col),
          (__attribute__((address_space(3))) void*)(As + ch * 8), 16, 0, 0);
    }
#pragma unroll
    for (int i = 0; i < 4; ++i) {
      int ch = i * 256 + tid;
      int row = ch >> 3;
      int col = (ch & 7) * 8;
      __builtin_amdgcn_global_load_lds(
          (const __attribute__((address_space(1))) void*)(Bw + (size_t)(n0 + row) * K + kt + col),
          (__attribute__((address_space(3))) void*)(Bs + ch * 8), 16, 0, 0);
    }
    __syncthreads();

    bf16x8 af[4][2], bf[4][2];
#pragma unroll
    for (int m = 0; m < 4; ++m)
#pragma unroll
      for (int kk = 0; kk < 2; ++kk)
        af[m][kk] = *(const bf16x8*)(As + (wr * 64 + m * 16 + lr) * 64 + kk * 32 + lk * 8);
#pragma unroll
    for (int nn = 0; nn < 4; ++nn)
#pragma unroll
      for (int kk = 0; kk < 2; ++kk)
        bf[nn][kk] = *(const bf16x8*)(Bs + (wc * 64 + nn * 16 + lr) * 64 + kk * 32 + lk * 8);

#pragma unroll
    for (int m = 0; m < 4; ++m)
#pragma unroll
      for (int nn = 0; nn < 4; ++nn)
#pragma unroll
        for (int kk = 0; kk < 2; ++kk)
          acc[m][nn] = __builtin_amdgcn_mfma_f32_16x16x32_bf16(af[m][kk], bf[nn][kk], acc[m][nn], 0, 0, 0);
    __syncthreads();
  }

  // C/D layout (m89): col = lane&15, row = (lane>>4)*4 + j
#pragma unroll
  for (int m = 0; m < 4; ++m) {
    size_t row = m0 + wr * 64 + m * 16 + lk * 4;
#pragma unroll
    for (int j = 0; j < 4; ++j) {
      float* cr = C + (row + j) * 256 + n0 + wc * 64 + lr;
#pragma unroll
      for (int nn = 0; nn < 4; ++nn)
        cr[nn * 16] = acc[m][nn][j];
    }
  }
}

// ---------------- per-channel sum / sumsq over rows of X [M][256] ----------------
// grid 128 (256 rows each), block 256 = channel; block b adds into shard b&7.
// Same-address atomic serialization ~34cyc/add (R11/R13/R14 sweep + R17 A/B);
// 8 shards -> 16 adds/address tail. sums layout: 8 shards x [sum 256 | sumsq 256].
__global__ void col_stats(const float* __restrict__ X, float* __restrict__ sums) {
  int c = threadIdx.x;
  size_t r0 = (size_t)blockIdx.x * 256;
  float s0 = 0, s1 = 0, s2 = 0, s3 = 0, q0 = 0, q1 = 0, q2 = 0, q3 = 0;
  for (int r = 0; r < 256; r += 4) {
    float v0 = X[(r0 + r + 0) * 256 + c];
    float v1 = X[(r0 + r + 1) * 256 + c];
    float v2 = X[(r0 + r + 2) * 256 + c];
    float v3 = X[(r0 + r + 3) * 256 + c];
    s0 += v0; q0 += v0 * v0;
    s1 += v1; q1 += v1 * v1;
    s2 += v2; q2 += v2 * v2;
    s3 += v3; q3 += v3 * v3;
  }
  float* sh = sums + (blockIdx.x & 7) * 512;
  atomicAdd(&sh[c], s0 + s1 + s2 + s3);
  atomicAdd(&sh[256 + c], q0 + q1 + q2 + q3);
}

// ---------------- BN (train) + ReLU + cast bf16: Y[M][256] ----------------
__global__ void bn_relu_kernel(const float* __restrict__ X, const float* __restrict__ sums,
                               const float* __restrict__ g, const float* __restrict__ be,
                               unsigned short* __restrict__ Y) {
  __shared__ float sc[256], sh[256];
  int t = threadIdx.x;
  {
    float s = 0.f, q = 0.f;
#pragma unroll
    for (int k = 0; k < 8; ++k) { s += sums[k * 512 + t]; q += sums[k * 512 + 256 + t]; }
    float m = s * (1.0f / 32768.0f);
    float v = q * (1.0f / 32768.0f) - m * m;
    float scale = g[t] * rsqrtf(v + 1e-5f);
    sc[t] = scale; sh[t] = be[t] - m * scale;
  }
  __syncthreads();
  const float4* X4 = (const float4*)X;
  ushort4* Y4 = (ushort4*)Y;
  for (size_t i = (size_t)blockIdx.x * 256 + t; i < (size_t)M_ * 64; i += 2048 * 256) {
    float4 x = X4[i];
    int c0 = (int)((i * 4) & 255);
    ushort4 o;
    o.x = f2bf(fmaxf(x.x * sc[c0 + 0] + sh[c0 + 0], 0.f));
    o.y = f2bf(fmaxf(x.y * sc[c0 + 1] + sh[c0 + 1], 0.f));
    o.z = f2bf(fmaxf(x.z * sc[c0 + 2] + sh[c0 + 2], 0.f));
    o.w = f2bf(fmaxf(x.w * sc[c0 + 3] + sh[c0 + 3], 0.f));
    Y4[i] = o;
  }
}

// ---------------- final: out[b][o][n] = relu(x + BN2(z)), tiled transpose ----------------
__global__ void final_kernel(const float* __restrict__ Z, const unsigned short* __restrict__ Xb,
                             const float* __restrict__ sums2, const float* __restrict__ g2,
                             const float* __restrict__ be2, float* __restrict__ out) {
  __shared__ float sc[64], sh[64];
  __shared__ float tile[64 * 65];
  int t = threadIdx.x;
  int o0 = blockIdx.y * 64;
  if (t < 64) {
    int c = o0 + t;
    float s = 0.f, q = 0.f;
#pragma unroll
    for (int k = 0; k < 8; ++k) { s += sums2[k * 512 + c]; q += sums2[k * 512 + 256 + c]; }
    float m = s * (1.0f / 32768.0f);
    float v = q * (1.0f / 32768.0f) - m * m;
    float scale = g2[c] * rsqrtf(v + 1e-5f);
    sc[t] = scale; sh[t] = be2[c] - m * scale;
  }
  __syncthreads();
  size_t m0 = (size_t)blockIdx.x * 64;
  int rl = t >> 4, cq = t & 15;
#pragma unroll
  for (int rr = 0; rr < 4; ++rr) {
    int row = rr * 16 + rl;
    size_t base = (m0 + row) * 256 + o0 + cq * 4;
    float4 z = *(const float4*)(Z + base);
    ushort4 x = *(const ushort4*)(Xb + base);
    int c = cq * 4;
    tile[row * 65 + c + 0] = fmaxf(z.x * sc[c + 0] + sh[c + 0] + bf2f(x.x), 0.f);
    tile[row * 65 + c + 1] = fmaxf(z.y * sc[c + 1] + sh[c + 1] + bf2f(x.y), 0.f);
    tile[row * 65 + c + 2] = fmaxf(z.z * sc[c + 2] + sh[c + 2] + bf2f(x.z), 0.f);
    tile[row * 65 + c + 3] = fmaxf(z.w * sc[c + 3] + sh[c + 3] + bf2f(x.w), 0.f);
  }
  __syncthreads();
  int b = (int)(m0 >> 13);
  int nbase = (int)(m0 & 8191);
  int orow = t >> 4, nq = t & 15;
#pragma unroll
  for (int ov = 0; ov < 4; ++ov) {
    int o = ov * 16 + orow;
    float4 v;
    v.x = tile[(nq * 4 + 0) * 65 + o];
    v.y = tile[(nq * 4 + 1) * 65 + o];
    v.z = tile[(nq * 4 + 2) * 65 + o];
    v.w = tile[(nq * 4 + 3) * 65 + o];
    *(float4*)(out + ((size_t)(b * 256 + o0 + o)) * 8192 + nbase + nq * 4) = v;
  }
}

extern "C" void kernel_launch(void* const* d_in, const int* in_sizes, int n_in,
                              void* d_out, int out_size, void* d_ws, size_t ws_size,
                              hipStream_t stream) {
  const float* xyz1    = (const float*)d_in[0];
  const float* xyz2    = (const float*)d_in[1];
  const float* points1 = (const float*)d_in[2];
  const float* points2 = (const float*)d_in[3];
  const float* W_fuse  = (const float*)d_in[4];
  // biases d_in[5], d_in[9], d_in[13] cancel exactly under training-mode BN
  const float* g_fuse  = (const float*)d_in[6];
  const float* be_fuse = (const float*)d_in[7];
  const float* W1      = (const float*)d_in[8];
  const float* g1      = (const float*)d_in[10];
  const float* be1     = (const float*)d_in[11];
  const float* W2      = (const float*)d_in[12];
  const float* g2      = (const float*)d_in[14];
  const float* be2     = (const float*)d_in[15];
  float* out = (float*)d_out;

  char* ws = (char*)d_ws;
  float* lin = (float*)ws;                   ws += (size_t)M_ * 256 * 4;   // 33.5 MB, reused 3x
  unsigned short* xb = (unsigned short*)ws;  ws += (size_t)M_ * 256 * 2;   // 16.8 MB
  unsigned short* np = (unsigned short*)ws;  ws += (size_t)M_ * 384 * 2;   // 25.2 MB (yb aliases np)
  unsigned short* yb = np;                                                  // np dead after fuse GEMM
  unsigned short* p2t = (unsigned short*)ws; ws += (size_t)B_ * S_ * 256 * 2; // 4.2 MB
  unsigned short* wb = (unsigned short*)ws;  ws += 229376 * 2;
  float* stats = (float*)ws;                 // 3 layers x 8 shards x 512 = 12288 floats

  // prologue: weights pack + stats zero (1 dispatch), both transposes (1 dispatch)
  pack_weights<<<896, 256, 0, stream>>>(W_fuse, W1, W2, wb, stats);
  transpose_both<<<dim3(1536, 1, B_), dim3(32, 8), 0, stream>>>(points1, np, points2, p2t);
  // 3-NN interp -> new_points[:, 128:384]
  knn_interp_kernel<<<dim3(N_ / 16, B_), 256, 0, stream>>>(xyz1, xyz2, p2t, np);
  // fuse layer
  gemm_bt<<<dim3(M_ / 128, 2), 256, 0, stream>>>(np, wb, lin, 384);
  col_stats<<<128, 256, 0, stream>>>(lin, stats);
  bn_relu_kernel<<<2048, 256, 0, stream>>>(lin, stats, g_fuse, be_fuse, xb);
  // residual block conv1
  gemm_bt<<<dim3(M_ / 128, 2), 256, 0, stream>>>(xb, wb + 98304, lin, 256);
  col_stats<<<128, 256, 0, stream>>>(lin, stats + 4096);
  bn_relu_kernel<<<2048, 256, 0, stream>>>(lin, stats + 4096, g1, be1, yb);
  // residual block conv2
  gemm_bt<<<dim3(M_ / 128, 2), 256, 0, stream>>>(yb, wb + 163840, lin, 256);
  col_stats<<<128, 256, 0, stream>>>(lin, stats + 8192);
  // BN2 + residual + relu + transpose to [B][256][N]
  final_kernel<<<dim3(M_ / 64, 4), 256, 0, stream>>>(lin, xb, stats + 8192, g2, be2, out);
}